// Round 10
// baseline (142.235 us; speedup 1.0000x reference)
//
#include <hip/hip_runtime.h>

// MpMaxPoolingMatch: out[b,t,m] = tanh( max_s sum_d lt[b,t,d]*km[m,d]*rt[b,s,d] )
// B=32, T=256, D=512, MP=20.
// R9: barrier-free K-loop. R2-R8 all pinned at 62-81us by the global_load_lds +
// barrier-per-step structure (vmcnt(0) drain each step). Now: full-K fp8 A-tile
// (128 x 512B, row stride 528B -> conflict-free) staged ONCE (one barrier total);
// B-frags loaded per-lane from L2-resident interleaved rt-fp8 straight to registers
// (double-buffered, ~2 steps ahead); loop = 4 ds_read + 4 global_load + 32 MFMA,
// no syncs. fp8 numerics proven by R8 (absmax 0.0). s-split + partial-max/combine
// + XCD swizzle retained from R5.

constexpr int TT = 256;   // T
constexpr int DD = 512;   // D
constexpr int NM = 20;    // MP
constexpr int NB = 32;    // B
constexpr int BM = 128;   // t-tile = s-tile
constexpr int NK = 8;     // K-steps of 64

typedef float f32x4  __attribute__((ext_vector_type(4)));
typedef long  i64x2  __attribute__((ext_vector_type(2)));

__device__ __forceinline__ unsigned pack_bf16(float lo, float hi) {
    unsigned ulo = __builtin_bit_cast(unsigned, lo);
    unsigned uhi = __builtin_bit_cast(unsigned, hi);
    return (ulo >> 16) | (uhi & 0xFFFF0000u);
}

// 4 fp32 -> 4 fp8 (e4m3, packed dword)
__device__ __forceinline__ unsigned pk4_fp8(float a, float b, float c, float d) {
    unsigned r = __builtin_amdgcn_cvt_pk_fp8_f32(a, b, 0, false);
    return __builtin_amdgcn_cvt_pk_fp8_f32(c, d, r, true);
}

__device__ __forceinline__ float blo(unsigned u) { return __builtin_bit_cast(float, u << 16); }
__device__ __forceinline__ float bhi(unsigned u) { return __builtin_bit_cast(float, u & 0xFFFF0000u); }

// ---------------- Phase 1a: lt fp32 -> bf16, row-major ----------------
__global__ __launch_bounds__(256)
void cast_lt_bf16(const float* __restrict__ lt, unsigned short* __restrict__ ltb)
{
    size_t base = ((size_t)blockIdx.x * 256 + threadIdx.x) * 8;
    float4 a = *(const float4*)(lt + base);
    float4 b = *(const float4*)(lt + base + 4);
    uint4 w;
    w.x = pack_bf16(a.x, a.y);
    w.y = pack_bf16(a.z, a.w);
    w.z = pack_bf16(b.x, b.y);
    w.w = pack_bf16(b.z, b.w);
    *(uint4*)(ltb + base) = w;
}

// ---------------- Phase 1b: rt fp32 -> fp8, group-interleaved rows (R8, verified) ----------------
// Row = 512 B fp8, 8 k-blocks of 64 B. 8-byte group q of a k-block holds source
// k-offset (q&1)*32 + (q>>1)*8, so 16-B chunk c = [slab0 g=c][slab1 g=c] = one
// lane's two K=32 fragments for BK=64.
__global__ __launch_bounds__(256)
void cast_rt_fp8(const float* __restrict__ rt, unsigned char* __restrict__ rtf)
{
    int t   = blockIdx.x * 256 + threadIdx.x;   // 0..524287
    int row = t >> 6;                           // b*256+s
    int g6  = t & 63;
    int kb  = g6 >> 3, q = g6 & 7;
    int src = ((q & 1) << 5) + ((q >> 1) << 3);
    const float* p = rt + (size_t)row * DD + kb * 64 + src;
    float4 a = *(const float4*)p;
    float4 b = *(const float4*)(p + 4);
    uint2 o;
    o.x = pk4_fp8(a.x, a.y, a.z, a.w);
    o.y = pk4_fp8(b.x, b.y, b.z, b.w);
    *(uint2*)(rtf + (size_t)row * DD + kb * 64 + q * 8) = o;
}

// ---------------- Main: 128t x 128s, barrier-free K-loop ----------------
// Ash: 128 rows x 33 chunks (16 B) = 67.6 KB; row stride 33 -> quarter-wave b128
// reads (16 rows, fixed chunk) hit all 8 bank groups x2 = conflict-free.
__global__ __launch_bounds__(256, 2)
void mp_match_reg(const unsigned short* __restrict__ ltb, const unsigned char* __restrict__ rtf,
                  const float* __restrict__ km, float* __restrict__ part)
{
    __shared__ __attribute__((aligned(16))) uint4 Ash[128 * 33];   // 67,584 B
    __shared__ __attribute__((aligned(16))) float maxbuf[2][BM];   // 1 KB

    // XCD swizzle: flat%8 == XCD; b%8 == XCD.
    const int f  = blockIdx.x;           // 0..2559
    const int c8 = f & 7;
    const int i  = f >> 3;               // 0..319
    const int b  = c8 + 8 * (i / 80);    // 0..31
    const int j  = i % 80;
    const int m  = j >> 2;               // 0..19
    const int t0 = ((j >> 1) & 1) * 128;
    const int s0 = (j & 1) * 128;
    const int sT = j & 1;

    const int tid  = threadIdx.x;
    const int w    = tid >> 6;
    const int lane = tid & 63;
    const int l15  = lane & 15;
    const int l4   = lane >> 4;
    const int wt   = (w & 1) * 64;       // wave t offset
    const int wsO  = (w >> 1) * 64;      // wave s offset

    const unsigned short* ltB = ltb + ((size_t)b * TT + t0) * DD;
    const unsigned char*  rtB = rtf + ((size_t)b * TT + s0) * DD;
    const float*          kmp = km  + (size_t)m * DD;

    auto loadB = [&](int kk, uint4* dst) {
#pragma unroll
        for (int jj = 0; jj < 4; ++jj)
            dst[jj] = *(const uint4*)(rtB + (size_t)(wsO + jj * 16 + l15) * DD + kk * 64 + l4 * 16);
    };

    uint4 bA[4], bB[4];
    loadB(0, bA);          // in flight through all of A staging + barrier
    loadB(1, bB);

    // ---- A staging: thread -> chunk-col cc (fixed 16 d-values), 16 rows.
    const int cc = tid & 31, kb = cc >> 2, cs = cc & 3;
    const int r0 = (tid >> 5) * 16;
    const int g0 = kb * 64 + cs * 8, g1 = g0 + 32;
    const float4 k0a = *(const float4*)(kmp + g0);
    const float4 k0b = *(const float4*)(kmp + g0 + 4);
    const float4 k1a = *(const float4*)(kmp + g1);
    const float4 k1b = *(const float4*)(kmp + g1 + 4);
#pragma unroll
    for (int r = 0; r < 16; ++r) {
        const unsigned short* src = ltB + (size_t)(r0 + r) * DD;
        uint4 h0 = *(const uint4*)(src + g0);   // 8 bf16, d = g0..g0+8
        uint4 h1 = *(const uint4*)(src + g1);   // 8 bf16, d = g1..g1+8
        uint4 o;
        o.x = pk4_fp8(blo(h0.x) * k0a.x, bhi(h0.x) * k0a.y, blo(h0.y) * k0a.z, bhi(h0.y) * k0a.w);
        o.y = pk4_fp8(blo(h0.z) * k0b.x, bhi(h0.z) * k0b.y, blo(h0.w) * k0b.z, bhi(h0.w) * k0b.w);
        o.z = pk4_fp8(blo(h1.x) * k1a.x, bhi(h1.x) * k1a.y, blo(h1.y) * k1a.z, bhi(h1.y) * k1a.w);
        o.w = pk4_fp8(blo(h1.z) * k1b.x, bhi(h1.z) * k1b.y, blo(h1.w) * k1b.z, bhi(h1.w) * k1b.w);
        Ash[(size_t)(r0 + r) * 33 + cc] = o;
    }
    __syncthreads();   // the ONLY pre-epilogue barrier

    auto loadA = [&](int kk, uint4* dst) {
#pragma unroll
        for (int ii = 0; ii < 4; ++ii)
            dst[ii] = Ash[(size_t)(wt + ii * 16 + l15) * 33 + kk * 4 + l4];
    };

    f32x4 acc[4][4] = {};
    uint4 aA[4], aB[4];
    loadA(0, aA);

#pragma unroll
    for (int kk = 0; kk < NK; ++kk) {
        uint4* bc = (kk & 1) ? bB : bA;
        uint4* an = (kk & 1) ? aA : aB;
        const uint4* ac = (kk & 1) ? aB : aA;
        if (kk + 1 < NK) loadA(kk + 1, an);
        i64x2 a2[4], b2[4];
#pragma unroll
        for (int ii = 0; ii < 4; ++ii) a2[ii] = __builtin_bit_cast(i64x2, ac[ii]);
#pragma unroll
        for (int jj = 0; jj < 4; ++jj) b2[jj] = __builtin_bit_cast(i64x2, bc[jj]);
#pragma unroll
        for (int ii = 0; ii < 4; ++ii)
#pragma unroll
            for (int jj = 0; jj < 4; ++jj)
                acc[ii][jj] = __builtin_amdgcn_mfma_f32_16x16x32_fp8_fp8(a2[ii].x, b2[jj].x, acc[ii][jj], 0, 0, 0);
#pragma unroll
        for (int ii = 0; ii < 4; ++ii)
#pragma unroll
            for (int jj = 0; jj < 4; ++jj)
                acc[ii][jj] = __builtin_amdgcn_mfma_f32_16x16x32_fp8_fp8(a2[ii].y, b2[jj].y, acc[ii][jj], 0, 0, 0);
        if (kk + 2 < NK) loadB(kk + 2, bc);   // refill freed buffer; ~1.5 steps ahead
    }

    // ---- Epilogue: max over this block's 128 s (no tanh). C: col(s)=lane&15, row(t)=(lane>>4)*4+reg.
#pragma unroll
    for (int ii = 0; ii < 4; ++ii) {
        f32x4 v = acc[ii][0];
#pragma unroll
        for (int jj = 1; jj < 4; ++jj) {
            v.x = fmaxf(v.x, acc[ii][jj].x);
            v.y = fmaxf(v.y, acc[ii][jj].y);
            v.z = fmaxf(v.z, acc[ii][jj].z);
            v.w = fmaxf(v.w, acc[ii][jj].w);
        }
#pragma unroll
        for (int off = 1; off < 16; off <<= 1) {
            v.x = fmaxf(v.x, __shfl_xor(v.x, off, 64));
            v.y = fmaxf(v.y, __shfl_xor(v.y, off, 64));
            v.z = fmaxf(v.z, __shfl_xor(v.z, off, 64));
            v.w = fmaxf(v.w, __shfl_xor(v.w, off, 64));
        }
        if (l15 == 0)
            *(f32x4*)&maxbuf[w >> 1][wt + ii * 16 + l4 * 4] = v;
    }
    __syncthreads();
    if (tid < BM) {
        float v = fmaxf(maxbuf[0][tid], maxbuf[1][tid]);
        part[(((size_t)sT * NB + b) * TT + t0 + tid) * NM + m] = v;
    }
}

// ---------------- Combine: out = tanh(max(p0, p1)) ----------------
__global__ __launch_bounds__(256)
void mp_combine(const float* __restrict__ part, float* __restrict__ out, int n)
{
    int idx = blockIdx.x * 256 + threadIdx.x;
    if (idx < n)
        out[idx] = tanhf(fmaxf(part[idx], part[(size_t)n + idx]));
}

// ---------------- R1 fallback (no workspace): bf16 MFMA, fp32 register staging ----------------
typedef short bf16x8 __attribute__((ext_vector_type(8)));

__global__ __launch_bounds__(256, 2)
void mp_match_kernel(const float* __restrict__ lt, const float* __restrict__ rt,
                     const float* __restrict__ km, float* __restrict__ out)
{
    __shared__ __attribute__((aligned(16))) unsigned short Ash[2][4][128][8];
    __shared__ __attribute__((aligned(16))) unsigned short Bsh2[2][4][256][8];
    __shared__ __attribute__((aligned(16))) float maxbuf[2][128];

    const int ttile = blockIdx.x, m = blockIdx.y, b = blockIdx.z;
    const int t0 = ttile * 128;
    const int tid = threadIdx.x, wave = tid >> 6, lane = tid & 63;
    const int l15 = lane & 15, l4 = lane >> 4;
    const int wt = (wave & 1) * 64, wsi = wave >> 1;

    const float* ltp = lt + ((size_t)b * TT + t0) * DD;
    const float* rtp = rt + (size_t)b * TT * DD;
    const float* kmp = km + (size_t)m * DD;
    const int a_t = tid >> 1, a_h = tid & 1;

    f32x4 acc[4][8] = {};

    auto stage = [&](int kk, int buf) {
        const int d0 = kk * 32;
        const float* ap = ltp + (size_t)a_t * DD + d0 + a_h * 16;
        const float* kp = kmp + d0 + a_h * 16;
#pragma unroll
        for (int q = 0; q < 2; ++q) {
            float4 x0 = *(const float4*)(ap + q * 8);
            float4 x1 = *(const float4*)(ap + q * 8 + 4);
            float4 k0 = *(const float4*)(kp + q * 8);
            float4 k1 = *(const float4*)(kp + q * 8 + 4);
            uint4 wv;
            wv.x = pack_bf16(x0.x * k0.x, x0.y * k0.y);
            wv.y = pack_bf16(x0.z * k0.z, x0.w * k0.w);
            wv.z = pack_bf16(x1.x * k1.x, x1.y * k1.y);
            wv.w = pack_bf16(x1.z * k1.z, x1.w * k1.w);
            *(uint4*)&Ash[buf][a_h * 2 + q][a_t][0] = wv;
        }
        const float* bp = rtp + (size_t)tid * DD + d0;
#pragma unroll
        for (int p = 0; p < 4; ++p) {
            float4 y0 = *(const float4*)(bp + p * 8);
            float4 y1 = *(const float4*)(bp + p * 8 + 4);
            uint4 wv;
            wv.x = pack_bf16(y0.x, y0.y);
            wv.y = pack_bf16(y0.z, y0.w);
            wv.z = pack_bf16(y1.x, y1.y);
            wv.w = pack_bf16(y1.z, y1.w);
            *(uint4*)&Bsh2[buf][p][tid][0] = wv;
        }
    };

    stage(0, 0);
    for (int kk = 0; kk < 16; ++kk) {
        const int buf = kk & 1;
        __syncthreads();
        bf16x8 af[4], bfv[8];
#pragma unroll
        for (int i2 = 0; i2 < 4; ++i2)
            af[i2] = *(const bf16x8*)&Ash[buf][l4][wt + i2 * 16 + l15][0];
#pragma unroll
        for (int j2 = 0; j2 < 8; ++j2)
            bfv[j2] = *(const bf16x8*)&Bsh2[buf][l4][wsi * 128 + j2 * 16 + l15][0];
        if (kk + 1 < 16) stage(kk + 1, buf ^ 1);
#pragma unroll
        for (int i2 = 0; i2 < 4; ++i2)
#pragma unroll
            for (int j2 = 0; j2 < 8; ++j2)
                acc[i2][j2] = __builtin_amdgcn_mfma_f32_16x16x32_bf16(af[i2], bfv[j2], acc[i2][j2], 0, 0, 0);
    }
#pragma unroll
    for (int i2 = 0; i2 < 4; ++i2) {
        f32x4 v = acc[i2][0];
#pragma unroll
        for (int j2 = 1; j2 < 8; ++j2) {
            v.x = fmaxf(v.x, acc[i2][j2].x); v.y = fmaxf(v.y, acc[i2][j2].y);
            v.z = fmaxf(v.z, acc[i2][j2].z); v.w = fmaxf(v.w, acc[i2][j2].w);
        }
#pragma unroll
        for (int off = 1; off < 16; off <<= 1) {
            v.x = fmaxf(v.x, __shfl_xor(v.x, off, 64));
            v.y = fmaxf(v.y, __shfl_xor(v.y, off, 64));
            v.z = fmaxf(v.z, __shfl_xor(v.z, off, 64));
            v.w = fmaxf(v.w, __shfl_xor(v.w, off, 64));
        }
        if (l15 == 0) *(f32x4*)&maxbuf[wsi][wt + i2 * 16 + l4 * 4] = v;
    }
    __syncthreads();
    if (tid < 128) {
        float v = fmaxf(maxbuf[0][tid], maxbuf[1][tid]);
        out[((size_t)b * TT + t0 + tid) * NM + m] = tanhf(v);
    }
}

extern "C" void kernel_launch(void* const* d_in, const int* in_sizes, int n_in,
                              void* d_out, int out_size, void* d_ws, size_t ws_size,
                              hipStream_t stream) {
    const float* lt  = (const float*)d_in[0];   // (32,256,512) fp32
    const float* rt  = (const float*)d_in[1];   // (32,256,512) fp32
    const float* km  = (const float*)d_in[2];   // (20,512) fp32
    float*       out = (float*)d_out;           // (32,256,20) fp32

    const size_t elems = (size_t)NB * TT * DD;                 // 4,194,304
    const size_t rtfB  = elems;                                // 4 MB fp8
    const size_t ltbB  = elems * sizeof(unsigned short);       // 8.39 MB bf16
    const int    nOut  = NB * TT * NM;                         // 163,840
    const size_t partB = 2 * (size_t)nOut * sizeof(float);     // 1.31 MB

    if (ws_size >= rtfB + ltbB + partB) {                      // 13.7 MB
        unsigned char*  rtf = (unsigned char*)d_ws;
        unsigned short* ltb = (unsigned short*)((char*)d_ws + rtfB);
        float* part = (float*)((char*)d_ws + rtfB + ltbB);
        cast_rt_fp8<<<(int)(elems / 8 / 256), 256, 0, stream>>>(rt, rtf);     // 2048
        cast_lt_bf16<<<(int)(elems / 8 / 256), 256, 0, stream>>>(lt, ltb);    // 2048
        mp_match_reg<<<2560, 256, 0, stream>>>(ltb, rtf, km, part);
        mp_combine<<<(nOut + 255) / 256, 256, 0, stream>>>(part, out, nOut);
    } else {
        mp_match_kernel<<<dim3(2, NM, NB), 256, 0, stream>>>(lt, rt, km, out);
    }
}

// Round 11
// 123.782 us; speedup vs baseline: 1.1491x; 1.1491x over previous
//
#include <hip/hip_runtime.h>

// MpMaxPoolingMatch: out[b,t,m] = tanh( max_s sum_d lt[b,t,d]*km[m,d]*rt[b,s,d] )
// B=32, T=256, D=512, MP=20.
// R10: lower the MFMA floor. R2-R9 pinned at 62-81us around a 20.7us fp8/bf16-rate
// floor (MfmaUtil ~24-29% = structural). Switch to mfma_scale_f32_16x16x128_f8f6f4
// with unit scales (e8m0=127): 4647 TF -> 9.2us floor, 4x fewer MFMA insts.
// K=128/lane-quad = 32 CONTIGUOUS k-bytes -> plain row-major fp8 for both operands
// (A/B symmetric, permutation cancels). BM=64 x full s=256, one pass, acc[4][4];
// A-tile (64x512B fp8, stride 33 chunks) staged once -> ONE barrier; B per-lane
// global loads double-buffered from L2/LLC; tanh fused. XCD swizzle kept.

constexpr int TT = 256;   // T
constexpr int DD = 512;   // D
constexpr int NM = 20;    // MP
constexpr int NB = 32;    // B
constexpr int BM = 64;    // t-tile
constexpr int NK = 4;     // K-steps of 128

typedef float f32x4 __attribute__((ext_vector_type(4)));
typedef int   i32x8 __attribute__((ext_vector_type(8)));

__device__ __forceinline__ unsigned pack_bf16(float lo, float hi) {
    unsigned ulo = __builtin_bit_cast(unsigned, lo);
    unsigned uhi = __builtin_bit_cast(unsigned, hi);
    return (ulo >> 16) | (uhi & 0xFFFF0000u);
}

// 4 fp32 -> 4 fp8 (e4m3, packed dword)
__device__ __forceinline__ unsigned pk4_fp8(float a, float b, float c, float d) {
    unsigned r = __builtin_amdgcn_cvt_pk_fp8_f32(a, b, 0, false);
    return __builtin_amdgcn_cvt_pk_fp8_f32(c, d, r, true);
}

__device__ __forceinline__ float blo(unsigned u) { return __builtin_bit_cast(float, u << 16); }
// hi bf16 without masking low bits: <0.4% perturbation, absorbed by fp8 quant + tanh
__device__ __forceinline__ float bhi(unsigned u) { return __builtin_bit_cast(float, u); }

__device__ __forceinline__ i32x8 mk8(uint4 a, uint4 b) {
    i32x8 v;
    v[0] = (int)a.x; v[1] = (int)a.y; v[2] = (int)a.z; v[3] = (int)a.w;
    v[4] = (int)b.x; v[5] = (int)b.y; v[6] = (int)b.z; v[7] = (int)b.w;
    return v;
}

// ---------------- Phase 1: lt fp32->bf16, rt fp32->fp8, both row-major ----------------
__global__ __launch_bounds__(256)
void cast_inputs(const float* __restrict__ lt, const float* __restrict__ rt,
                 unsigned short* __restrict__ ltb, unsigned char* __restrict__ rtf)
{
    const int half = (int)gridDim.x >> 1;
    if ((int)blockIdx.x < half) {
        size_t base = ((size_t)blockIdx.x * 256 + threadIdx.x) * 8;
        float4 a = *(const float4*)(lt + base);
        float4 b = *(const float4*)(lt + base + 4);
        uint4 w;
        w.x = pack_bf16(a.x, a.y);
        w.y = pack_bf16(a.z, a.w);
        w.z = pack_bf16(b.x, b.y);
        w.w = pack_bf16(b.z, b.w);
        *(uint4*)(ltb + base) = w;
    } else {
        size_t base = ((size_t)(blockIdx.x - half) * 256 + threadIdx.x) * 8;
        float4 a = *(const float4*)(rt + base);
        float4 b = *(const float4*)(rt + base + 4);
        uint2 o;
        o.x = pk4_fp8(a.x, a.y, a.z, a.w);
        o.y = pk4_fp8(b.x, b.y, b.z, b.w);
        *(uint2*)(rtf + base) = o;
    }
}

// ---------------- Main: 64t x 256s, MX fp8 K=128, one barrier ----------------
__global__ __launch_bounds__(256, 2)
void mp_match_mx(const unsigned short* __restrict__ ltb, const unsigned char* __restrict__ rtf,
                 const float* __restrict__ km, float* __restrict__ out)
{
    __shared__ __attribute__((aligned(16))) uint4 Ash[BM * 33];   // 33.8 KB, stride 33 -> 2-way free
    __shared__ __attribute__((aligned(16))) float maxbuf[4][BM];  // 1 KB

    // XCD swizzle: flat%8 == XCD; b%8 == XCD.
    const int f  = blockIdx.x;           // 0..2559
    const int c8 = f & 7;
    const int i  = f >> 3;               // 0..319
    const int b  = c8 + 8 * (i / 80);    // 0..31
    const int j  = i % 80;
    const int m  = j >> 2;               // 0..19
    const int t0 = (j & 3) * BM;         // 0,64,128,192

    const int tid  = threadIdx.x;
    const int w    = tid >> 6;           // wave = s-quarter
    const int lane = tid & 63;
    const int l15  = lane & 15;
    const int l4   = lane >> 4;          // k-block-of-32 within K=128
    const int ws   = w * 64;             // wave's s offset

    const unsigned short* ltB = ltb + ((size_t)b * TT + t0) * DD;
    const unsigned char*  rtB = rtf + (size_t)b * TT * DD;
    const float*          kmp = km  + (size_t)m * DD;

    // B frags: row = ws + jj*16 + l15, bytes kk*128 + l4*32 .. +32 (32B-aligned)
    auto loadB = [&](int kk, uint4* d) {
#pragma unroll
        for (int jj = 0; jj < 4; ++jj) {
            const unsigned char* p = rtB + (size_t)(ws + jj * 16 + l15) * DD + kk * 128 + l4 * 32;
            d[jj * 2]     = *(const uint4*)p;
            d[jj * 2 + 1] = *(const uint4*)(p + 16);
        }
    };

    uint4 b0[8], b1[8];
    loadB(0, b0);   // in flight through A staging

    // ---- A staging: thread -> chunk-col cc (d = cc*16..+16), rows r0..r0+8.
    const int cc = tid & 31, r0 = (tid >> 5) * 8;
    const float4 kA = *(const float4*)(kmp + cc * 16);
    const float4 kB = *(const float4*)(kmp + cc * 16 + 4);
    const float4 kC = *(const float4*)(kmp + cc * 16 + 8);
    const float4 kD = *(const float4*)(kmp + cc * 16 + 12);
#pragma unroll
    for (int r = 0; r < 8; ++r) {
        const unsigned short* src = ltB + (size_t)(r0 + r) * DD + cc * 16;
        uint4 h0 = *(const uint4*)src;        // bf16 d..d+7
        uint4 h1 = *(const uint4*)(src + 8);  // bf16 d+8..d+15
        uint4 o;
        o.x = pk4_fp8(blo(h0.x) * kA.x, bhi(h0.x) * kA.y, blo(h0.y) * kA.z, bhi(h0.y) * kA.w);
        o.y = pk4_fp8(blo(h0.z) * kB.x, bhi(h0.z) * kB.y, blo(h0.w) * kB.z, bhi(h0.w) * kB.w);
        o.z = pk4_fp8(blo(h1.x) * kC.x, bhi(h1.x) * kC.y, blo(h1.y) * kC.z, bhi(h1.y) * kC.w);
        o.w = pk4_fp8(blo(h1.z) * kD.x, bhi(h1.z) * kD.y, blo(h1.w) * kD.z, bhi(h1.w) * kD.w);
        Ash[(r0 + r) * 33 + cc] = o;
    }
    __syncthreads();   // the ONLY pre-epilogue barrier

    // A frags: row = ii*16 + l15, chunks kk*8 + l4*2 (+1)
    auto loadA = [&](int kk, uint4* d) {
#pragma unroll
        for (int ii = 0; ii < 4; ++ii) {
            int base = (ii * 16 + l15) * 33 + kk * 8 + l4 * 2;
            d[ii * 2]     = Ash[base];
            d[ii * 2 + 1] = Ash[base + 1];
        }
    };

    f32x4 acc[4][4] = {};
    uint4 aA[8], aB[8];
    loadA(0, aA);

#pragma unroll
    for (int kk = 0; kk < NK; ++kk) {
        uint4* bc = (kk & 1) ? b1 : b0;
        uint4* bn = (kk & 1) ? b0 : b1;
        const uint4* ac = (kk & 1) ? aB : aA;
        uint4* an = (kk & 1) ? aA : aB;
        if (kk + 1 < NK) {
            loadB(kk + 1, bn);   // global, ~1 step (~1100 cyc) ahead
            loadA(kk + 1, an);   // LDS
        }
        i32x8 av[4], bv[4];
#pragma unroll
        for (int ii = 0; ii < 4; ++ii) av[ii] = mk8(ac[ii * 2], ac[ii * 2 + 1]);
#pragma unroll
        for (int jj = 0; jj < 4; ++jj) bv[jj] = mk8(bc[jj * 2], bc[jj * 2 + 1]);
#pragma unroll
        for (int ii = 0; ii < 4; ++ii)
#pragma unroll
            for (int jj = 0; jj < 4; ++jj)
                acc[ii][jj] = __builtin_amdgcn_mfma_scale_f32_16x16x128_f8f6f4(
                    av[ii], bv[jj], acc[ii][jj], 0, 0, 0, 127, 0, 127);  // fmt=fp8, scales=1.0
    }

    // ---- Epilogue: max over s. C layout: col(s)=lane&15, row(t)=(lane>>4)*4+reg.
#pragma unroll
    for (int ii = 0; ii < 4; ++ii) {
        f32x4 v = acc[ii][0];
#pragma unroll
        for (int jj = 1; jj < 4; ++jj) {
            v.x = fmaxf(v.x, acc[ii][jj].x);
            v.y = fmaxf(v.y, acc[ii][jj].y);
            v.z = fmaxf(v.z, acc[ii][jj].z);
            v.w = fmaxf(v.w, acc[ii][jj].w);
        }
#pragma unroll
        for (int off = 1; off < 16; off <<= 1) {
            v.x = fmaxf(v.x, __shfl_xor(v.x, off, 64));
            v.y = fmaxf(v.y, __shfl_xor(v.y, off, 64));
            v.z = fmaxf(v.z, __shfl_xor(v.z, off, 64));
            v.w = fmaxf(v.w, __shfl_xor(v.w, off, 64));
        }
        if (l15 == 0)
            *(f32x4*)&maxbuf[w][ii * 16 + l4 * 4] = v;
    }
    __syncthreads();
    if (tid < BM) {
        float v = fmaxf(fmaxf(maxbuf[0][tid], maxbuf[1][tid]),
                        fmaxf(maxbuf[2][tid], maxbuf[3][tid]));
        out[((size_t)b * TT + t0 + tid) * NM + m] = tanhf(v);
    }
}

// ---------------- R1 fallback (no workspace): bf16 MFMA, fp32 register staging ----------------
typedef short bf16x8 __attribute__((ext_vector_type(8)));

__global__ __launch_bounds__(256, 2)
void mp_match_kernel(const float* __restrict__ lt, const float* __restrict__ rt,
                     const float* __restrict__ km, float* __restrict__ out)
{
    __shared__ __attribute__((aligned(16))) unsigned short Ash[2][4][128][8];
    __shared__ __attribute__((aligned(16))) unsigned short Bsh2[2][4][256][8];
    __shared__ __attribute__((aligned(16))) float maxbuf[2][128];

    const int ttile = blockIdx.x, m = blockIdx.y, b = blockIdx.z;
    const int t0 = ttile * 128;
    const int tid = threadIdx.x, wave = tid >> 6, lane = tid & 63;
    const int l15 = lane & 15, l4 = lane >> 4;
    const int wt = (wave & 1) * 64, wsi = wave >> 1;

    const float* ltp = lt + ((size_t)b * TT + t0) * DD;
    const float* rtp = rt + (size_t)b * TT * DD;
    const float* kmp = km + (size_t)m * DD;
    const int a_t = tid >> 1, a_h = tid & 1;

    f32x4 acc[4][8] = {};

    auto stage = [&](int kk, int buf) {
        const int d0 = kk * 32;
        const float* ap = ltp + (size_t)a_t * DD + d0 + a_h * 16;
        const float* kp = kmp + d0 + a_h * 16;
#pragma unroll
        for (int q = 0; q < 2; ++q) {
            float4 x0 = *(const float4*)(ap + q * 8);
            float4 x1 = *(const float4*)(ap + q * 8 + 4);
            float4 k0 = *(const float4*)(kp + q * 8);
            float4 k1 = *(const float4*)(kp + q * 8 + 4);
            uint4 wv;
            wv.x = pack_bf16(x0.x * k0.x, x0.y * k0.y);
            wv.y = pack_bf16(x0.z * k0.z, x0.w * k0.w);
            wv.z = pack_bf16(x1.x * k1.x, x1.y * k1.y);
            wv.w = pack_bf16(x1.z * k1.z, x1.w * k1.w);
            *(uint4*)&Ash[buf][a_h * 2 + q][a_t][0] = wv;
        }
        const float* bp = rtp + (size_t)tid * DD + d0;
#pragma unroll
        for (int p = 0; p < 4; ++p) {
            float4 y0 = *(const float4*)(bp + p * 8);
            float4 y1 = *(const float4*)(bp + p * 8 + 4);
            uint4 wv;
            wv.x = pack_bf16(y0.x, y0.y);
            wv.y = pack_bf16(y0.z, y0.w);
            wv.z = pack_bf16(y1.x, y1.y);
            wv.w = pack_bf16(y1.z, y1.w);
            *(uint4*)&Bsh2[buf][p][tid][0] = wv;
        }
    };

    stage(0, 0);
    for (int kk = 0; kk < 16; ++kk) {
        const int buf = kk & 1;
        __syncthreads();
        bf16x8 af[4], bfv[8];
#pragma unroll
        for (int i2 = 0; i2 < 4; ++i2)
            af[i2] = *(const bf16x8*)&Ash[buf][l4][wt + i2 * 16 + l15][0];
#pragma unroll
        for (int j2 = 0; j2 < 8; ++j2)
            bfv[j2] = *(const bf16x8*)&Bsh2[buf][l4][wsi * 128 + j2 * 16 + l15][0];
        if (kk + 1 < 16) stage(kk + 1, buf ^ 1);
#pragma unroll
        for (int i2 = 0; i2 < 4; ++i2)
#pragma unroll
            for (int j2 = 0; j2 < 8; ++j2)
                acc[i2][j2] = __builtin_amdgcn_mfma_f32_16x16x32_bf16(af[i2], bfv[j2], acc[i2][j2], 0, 0, 0);
    }
#pragma unroll
    for (int i2 = 0; i2 < 4; ++i2) {
        f32x4 v = acc[i2][0];
#pragma unroll
        for (int j2 = 1; j2 < 8; ++j2) {
            v.x = fmaxf(v.x, acc[i2][j2].x); v.y = fmaxf(v.y, acc[i2][j2].y);
            v.z = fmaxf(v.z, acc[i2][j2].z); v.w = fmaxf(v.w, acc[i2][j2].w);
        }
#pragma unroll
        for (int off = 1; off < 16; off <<= 1) {
            v.x = fmaxf(v.x, __shfl_xor(v.x, off, 64));
            v.y = fmaxf(v.y, __shfl_xor(v.y, off, 64));
            v.z = fmaxf(v.z, __shfl_xor(v.z, off, 64));
            v.w = fmaxf(v.w, __shfl_xor(v.w, off, 64));
        }
        if (l15 == 0) *(f32x4*)&maxbuf[wsi][wt + i2 * 16 + l4 * 4] = v;
    }
    __syncthreads();
    if (tid < 128) {
        float v = fmaxf(maxbuf[0][tid], maxbuf[1][tid]);
        out[((size_t)b * TT + t0 + tid) * NM + m] = tanhf(v);
    }
}

extern "C" void kernel_launch(void* const* d_in, const int* in_sizes, int n_in,
                              void* d_out, int out_size, void* d_ws, size_t ws_size,
                              hipStream_t stream) {
    const float* lt  = (const float*)d_in[0];   // (32,256,512) fp32
    const float* rt  = (const float*)d_in[1];   // (32,256,512) fp32
    const float* km  = (const float*)d_in[2];   // (20,512) fp32
    float*       out = (float*)d_out;           // (32,256,20) fp32

    const size_t elems = (size_t)NB * TT * DD;                 // 4,194,304
    const size_t ltbB  = elems * sizeof(unsigned short);       // 8.39 MB bf16
    const size_t rtfB  = elems;                                // 4.19 MB fp8

    if (ws_size >= ltbB + rtfB) {                              // 12.6 MB
        unsigned short* ltb = (unsigned short*)d_ws;
        unsigned char*  rtf = (unsigned char*)((char*)d_ws + ltbB);
        cast_inputs<<<4096, 256, 0, stream>>>(lt, rt, ltb, rtf);
        mp_match_mx<<<2560, 256, 0, stream>>>(ltb, rtf, km, out);
    } else {
        mp_match_kernel<<<dim3(2, NM, NB), 256, 0, stream>>>(lt, rt, km, out);
    }
}